// Round 22
// baseline (1211.382 us; speedup 1.0000x reference)
//
#include <hip/hip_runtime.h>
#include <math.h>

constexpr int B_  = 64;
constexpr int LQ_ = 64;
constexpr int LS_ = 512;
constexpr int S_  = 512;
#define NEGV (-1e6f)
#define MARGIN 0.0625f

typedef __attribute__((ext_vector_type(8))) short bf16x8;
typedef __attribute__((ext_vector_type(4))) float f32x4;

__device__ inline unsigned short f2bf_rn(float x) {
    unsigned u = __builtin_bit_cast(unsigned, x);
    unsigned r = (u + 0x7FFFu + ((u >> 16) & 1u)) >> 16;
    return (unsigned short)r;
}

// ---------------- shared-memory overlay (max = score: 88064 B) -------------
union __attribute__((aligned(16))) Smem {
    struct { float att[64]; float wsm[64]; float qs[512]; float red[8][512]; } qp;
    struct { float scq[32]; float scu[32]; } pp;
    struct { short As[2][4096]; short Bs[2][16384];
             float int_l[512]; float wsm_l[512]; float sm_red[128][4]; } sc;
    struct { float s_l[512]; float qs_l[512]; float us_l[512]; float arow[512];
             float red[8][512]; float wred[8]; int wcnt[8]; int cand[8]; } rs;
    struct { float s_l[512]; float wred[8]; int wcnt[8]; int cand[8];
             float scq[32]; float scu[32]; int best_sh; } pe;
};

// ---------------- grid-wide sync (all 256 blocks co-resident) --------------
__device__ __forceinline__ void gsync(unsigned* cnt, unsigned target) {
    __threadfence();
    __syncthreads();
    if (threadIdx.x == 0) {
        __hip_atomic_fetch_add(cnt, 1u, __ATOMIC_ACQ_REL, __HIP_MEMORY_SCOPE_AGENT);
        unsigned v;
        do {
            __builtin_amdgcn_s_sleep(2);
            v = __hip_atomic_load(cnt, __ATOMIC_ACQUIRE, __HIP_MEMORY_SCOPE_AGENT);
        } while (v < target);
    }
    __syncthreads();
    __threadfence();
}

// ---------------- candidate selection (block-wide) ----------------
__device__ inline int select_cands(const float* s_l, int t, int lane, int w,
                                   float* wred, int* wcnt, int* cand)
{
    float v = s_l[t];
    #pragma unroll
    for (int off = 32; off >= 1; off >>= 1)
        v = fmaxf(v, __shfl_xor(v, off));
    if (lane == 0) wred[w] = v;
    __syncthreads();
    float m = wred[0];
    #pragma unroll
    for (int k = 1; k < 8; ++k) m = fmaxf(m, wred[k]);
    float th = m - MARGIN;
    bool flag = s_l[t] >= th;
    unsigned long long bal = __ballot(flag);
    int rank = __popcll(bal & ((1ull << lane) - 1ull));
    if (lane == 0) wcnt[w] = (int)__popcll(bal);
    __syncthreads();
    int off = 0, total = 0;
    #pragma unroll
    for (int k = 0; k < 8; ++k) { if (k < w) off += wcnt[k]; total += wcnt[k]; }
    if (flag) { int pos = off + rank; if (pos < 8) cand[pos] = t; }
    __syncthreads();
    return total < 8 ? total : 8;
}

// ---------------- score phase (r13 body: reg-A + 2-buf DMA-B) --------------
template <bool END>
__device__ void score_phase(Smem& sm, int blk,
                            const float* __restrict__ es, const short* __restrict__ Wc,
                            const float* __restrict__ inter, const float* __restrict__ Wsmall,
                            const int* __restrict__ slen, const int* __restrict__ sp,
                            float* __restrict__ out)
{
    const int t = threadIdx.x;
    const int lane = t & 63, wid = t >> 6;
    const int wr = wid >> 2, wc = wid & 3;
    const int l15 = lane & 15, l4 = lane >> 4;

    int xcd = blk & 7, slot = blk >> 3;
    int b  = xcd * 8 + (slot >> 2);
    int rc = slot & 3;

    sm.sc.int_l[t] = inter[b * S_ + t];
    sm.sc.wsm_l[t] = Wsmall[t];

    const char* Bbase = (const char*)(Wc + (size_t)b * 262144);

    f32x4 acc[4][8];
    #pragma unroll
    for (int r = 0; r < 4; ++r)
        #pragma unroll
        for (int c = 0; c < 8; ++c)
            acc[r][c] = (f32x4){0.f, 0.f, 0.f, 0.f};

    const int arow = t >> 2, akc = t & 3;
    const float* aptr = es + ((size_t)(b * LS_ + rc * 128 + arow)) * S_ + akc * 8;

    auto stageB = [&](int i, int buf) {
        const char* gb = Bbase + (size_t)i * 32768 + t * 16;
        char* lb = (char*)sm.sc.Bs[buf] + t * 16;
        #pragma unroll
        for (int q = 0; q < 4; ++q)
            __builtin_amdgcn_global_load_lds(
                (const __attribute__((address_space(1))) void*)(gb + q * 8192),
                (__attribute__((address_space(3))) void*)(lb + q * 8192), 16, 0, 0);
    };
    auto buildA = [&](int buf, float4 a0, float4 a1) {
        uint4 HA;
        HA.x = f2bf_rn(a0.x) | ((unsigned)f2bf_rn(a0.y) << 16);
        HA.y = f2bf_rn(a0.z) | ((unsigned)f2bf_rn(a0.w) << 16);
        HA.z = f2bf_rn(a1.x) | ((unsigned)f2bf_rn(a1.y) << 16);
        HA.w = f2bf_rn(a1.z) | ((unsigned)f2bf_rn(a1.w) << 16);
        *(uint4*)&sm.sc.As[buf][akc * 1024 + arow * 8] = HA;
    };

    float4 s0 = *(const float4*)(aptr);
    float4 s1 = *(const float4*)(aptr + 4);
    __syncthreads();           // int_l/wsm_l visible; smem phase boundary
    buildA(0, s0, s1);
    stageB(0, 0);
    float4 n0 = *(const float4*)(aptr + 32);
    float4 n1 = *(const float4*)(aptr + 36);

    for (int i = 0; i < 16; ++i) {
        const int buf = i & 1;
        if (i + 1 < 16) {
            stageB(i + 1, buf ^ 1);
            buildA(buf ^ 1, n0, n1);
            if (i + 2 < 16) {
                n0 = *(const float4*)(aptr + (i + 2) * 32);
                n1 = *(const float4*)(aptr + (i + 2) * 32 + 4);
            }
            asm volatile("s_waitcnt vmcnt(4) lgkmcnt(0)" ::: "memory");
        } else {
            asm volatile("s_waitcnt vmcnt(0) lgkmcnt(0)" ::: "memory");
        }
        __builtin_amdgcn_s_barrier();

        bf16x8 ah[4];
        #pragma unroll
        for (int r = 0; r < 4; ++r) {
            int rowp = wr * 64 + r * 16 + l15;
            ah[r] = *(const bf16x8*)&sm.sc.As[buf][l4 * 1024 + rowp * 8];
        }
        #pragma unroll
        for (int c = 0; c < 8; ++c) {
            int col = wc * 128 + c * 16 + l15;
            bf16x8 bh = *(const bf16x8*)&sm.sc.Bs[buf][l4 * 4096 + col * 8];
            #pragma unroll
            for (int r = 0; r < 4; ++r)
                acc[r][c] = __builtin_amdgcn_mfma_f32_16x16x32_bf16(ah[r], bh, acc[r][c], 0, 0, 0);
        }
        asm volatile("s_waitcnt lgkmcnt(0)" ::: "memory");
        __builtin_amdgcn_s_barrier();
    }

    #pragma unroll
    for (int r = 0; r < 4; ++r) {
        #pragma unroll
        for (int jj = 0; jj < 4; ++jj) {
            float pr = 0.f;
            #pragma unroll
            for (int c = 0; c < 8; ++c) {
                int col = wc * 128 + c * 16 + l15;
                float v = acc[r][c][jj] + sm.sc.int_l[col];
                v = fmaxf(v, 0.f);
                pr = fmaf(v, sm.sc.wsm_l[col], pr);
            }
            pr += __shfl_xor(pr, 1);
            pr += __shfl_xor(pr, 2);
            pr += __shfl_xor(pr, 4);
            pr += __shfl_xor(pr, 8);
            if (l15 == 0) sm.sc.sm_red[wr * 64 + r * 16 + l4 * 4 + jj][wc] = pr;
        }
    }
    __syncthreads();
    if (t < 128) {
        int l = rc * 128 + t;
        float s = sm.sc.sm_red[t][0] + sm.sc.sm_red[t][1] + sm.sc.sm_red[t][2] + sm.sc.sm_red[t][3];
        if (l >= slen[b]) s += NEGV;
        if (END) { if (l < sp[b]) s += NEGV; }
        out[b * LS_ + l] = s;
    }
}

// ---------------- rescue phase (one candidate per logical block) -----------
template <bool END>
__device__ void rescue_phase(Smem& sm, int lb,
                             const float* __restrict__ support, const float* __restrict__ q_state,
                             const int* __restrict__ sp, const float* __restrict__ Wbig,
                             const float* __restrict__ inter, const float* __restrict__ Wsmall,
                             const float* __restrict__ scores, float* __restrict__ part)
{
    int b = lb >> 3, cslot = lb & 7;
    int t = threadIdx.x, lane = t & 63, w = t >> 6;

    sm.rs.s_l[t]  = scores[b * S_ + t];
    sm.rs.qs_l[t] = q_state[b * S_ + t];
    if (END) {
        int spv = sp[b];
        sm.rs.us_l[t] = support[((size_t)(b * LS_ + spv)) * S_ + t];
    }
    __syncthreads();

    int cnt = select_cands(sm.rs.s_l, t, lane, w, sm.rs.wred, sm.rs.wcnt, sm.rs.cand);
    bool skip = (cnt == 1 || cslot >= cnt);
    if (!skip) {
        int ci = sm.rs.cand[cslot];
        sm.rs.arow[t] = support[((size_t)(b * LS_ + ci)) * S_ + t];
        __syncthreads();

        const float* W1 = Wbig;
        const float* W2 = Wbig + (size_t)S_ * S_;
        const float* W3 = Wbig + (size_t)2 * S_ * S_;
        const int d0 = w * 64;

        float z[8];
        #pragma unroll
        for (int j = 0; j < 8; ++j) z[j] = 0.f;

        #pragma unroll 2
        for (int dd = 0; dd < 64; ++dd) {
            int d = d0 + dd;
            float a  = sm.rs.arow[d];
            float qa = sm.rs.qs_l[d] * a;
            float ua = END ? sm.rs.us_l[d] * a : 0.f;
            const float* r1 = W1 + (size_t)d * S_ + lane;
            const float* r2 = W2 + (size_t)d * S_ + lane;
            const float* r3 = W3 + (size_t)d * S_ + lane;
            #pragma unroll
            for (int j = 0; j < 8; ++j) {
                if (END)
                    z[j] = fmaf(ua, r1[64 * j], fmaf(qa, r2[64 * j], fmaf(a, r3[64 * j], z[j])));
                else
                    z[j] = fmaf(qa, r1[64 * j], fmaf(a, r2[64 * j], z[j]));
            }
        }
        #pragma unroll
        for (int j = 0; j < 8; ++j) sm.rs.red[w][lane + 64 * j] = z[j];
        __syncthreads();

        float v = 0.f;
        #pragma unroll
        for (int ww = 0; ww < 8; ++ww) v += sm.rs.red[ww][t];
        float p = fmaxf(v + inter[b * S_ + t], 0.f) * Wsmall[t];
        #pragma unroll
        for (int off = 32; off >= 1; off >>= 1)
            p += __shfl_xor(p, off);
        if (lane == 0) sm.rs.wred[w] = p;
        __syncthreads();
        if (t == 0) {
            float e = ((sm.rs.wred[0] + sm.rs.wred[1]) + (sm.rs.wred[2] + sm.rs.wred[3])) +
                      ((sm.rs.wred[4] + sm.rs.wred[5]) + (sm.rs.wred[6] + sm.rs.wred[7]));
            part[b * 8 + cslot] = e;
        }
    }
    __syncthreads();
}

// ---------------- weight-fold helper (writes one (i,b) Wc slice) -----------
template <bool END>
__device__ void fold_slice(Smem& sm, int i, int b,
                           const float* __restrict__ W, const float* __restrict__ q_state,
                           const float* __restrict__ es, int best, short* __restrict__ Wc)
{
    int col = threadIdx.x;
    if (col < 32) sm.pe.scq[col] = q_state[b * S_ + i * 32 + col];
    if (END && col >= 32 && col < 64)
        sm.pe.scu[col - 32] = es[((size_t)(b * LS_ + best)) * S_ + i * 32 + (col - 32)];
    __syncthreads();

    unsigned short h[32];
    #pragma unroll
    for (int d = 0; d < 32; ++d) {
        int D = i * 32 + d;
        float v;
        if (!END)
            v = fmaf(sm.pe.scq[d], W[(size_t)D * S_ + col], W[(size_t)(S_ + D) * S_ + col]);
        else
            v = fmaf(sm.pe.scu[d], W[(size_t)D * S_ + col],
                fmaf(sm.pe.scq[d], W[(size_t)(S_ + D) * S_ + col],
                     W[(size_t)(2 * S_ + D) * S_ + col]));
        h[d] = f2bf_rn(v);
    }
    size_t base = (size_t)b * 262144 + (size_t)i * 16384 + (size_t)col * 8;
    #pragma unroll
    for (int kc = 0; kc < 4; ++kc) {
        uint4 H;
        H.x = h[kc*8+0] | ((unsigned)h[kc*8+1] << 16);
        H.y = h[kc*8+2] | ((unsigned)h[kc*8+3] << 16);
        H.z = h[kc*8+4] | ((unsigned)h[kc*8+5] << 16);
        H.w = h[kc*8+6] | ((unsigned)h[kc*8+7] << 16);
        *(uint4*)&Wc[base + kc * 4096] = H;
    }
    __syncthreads();
}

// ---------------- the mega-kernel ----------------
__global__ __launch_bounds__(512, 2)
void mega_kernel(const float* __restrict__ eq, const float* __restrict__ es,
                 const int* __restrict__ qlen, const int* __restrict__ slen,
                 const float* __restrict__ W_qa,
                 const float* __restrict__ W_qsi, const float* __restrict__ b_qsi,
                 const float* __restrict__ W_qs, const float* __restrict__ W_ss,
                 const float* __restrict__ W_qei, const float* __restrict__ b_qei,
                 const float* __restrict__ W_qe, const float* __restrict__ W_es,
                 float* __restrict__ q_state, float* __restrict__ qsi, float* __restrict__ qei,
                 float* __restrict__ part, int* __restrict__ sp_ws, short* __restrict__ Wc,
                 unsigned* __restrict__ sync_cnt,
                 float* __restrict__ start_scores, float* __restrict__ end_scores,
                 float* __restrict__ pred_start, float* __restrict__ pred_end)
{
    __shared__ Smem sm;
    const int blk = blockIdx.x;
    const int t = threadIdx.x, lane = t & 63, w = t >> 6;
    unsigned tgt = 0;

    // ---------------- P0: qpool + inter (blocks 0..127) ----------------
    if (blk < 128) {
        int b = blk & 63;
        int which = blk >> 6;
        const float* W  = which ? W_qei : W_qsi;
        const float* bi = which ? b_qei : b_qsi;
        float*       o  = which ? qei   : qsi;
        const float* eqb = eq + (size_t)b * LQ_ * S_;

        #pragma unroll
        for (int k = 0; k < 8; ++k) {
            int q = w + 8 * k;
            const float* row = eqb + q * S_;
            float s = 0.f;
            #pragma unroll
            for (int j = 0; j < 8; ++j)
                s = fmaf(row[lane + 64 * j], W_qa[lane + 64 * j], s);
            #pragma unroll
            for (int off = 32; off >= 1; off >>= 1)
                s += __shfl_xor(s, off);
            if (lane == 0) sm.qp.att[q] = s;
        }
        __syncthreads();

        if (w == 0) {
            int L = qlen[b];
            float v = sm.qp.att[lane] + ((lane < L) ? 0.f : NEGV);
            float m = v;
            #pragma unroll
            for (int off = 32; off >= 1; off >>= 1)
                m = fmaxf(m, __shfl_xor(m, off));
            float e = expf(v - m);
            float sum = e;
            #pragma unroll
            for (int off = 32; off >= 1; off >>= 1)
                sum += __shfl_xor(sum, off);
            sm.qp.wsm[lane] = e / sum;
        }
        __syncthreads();

        {
            float acc = 0.f;
            #pragma unroll 8
            for (int q = 0; q < LQ_; ++q)
                acc = fmaf(sm.qp.wsm[q], eqb[q * S_ + t], acc);
            sm.qp.qs[t] = acc;
            if (which == 0) q_state[b * S_ + t] = acc;
        }
        __syncthreads();

        {
            float z[8];
            #pragma unroll
            for (int k = 0; k < 8; ++k) z[k] = 0.f;
            const int d0 = w * 64;
            #pragma unroll 4
            for (int dd = 0; dd < 64; ++dd) {
                int d = d0 + dd;
                float q = sm.qp.qs[d];
                const float* row = W + (size_t)d * S_ + lane;
                #pragma unroll
                for (int k = 0; k < 8; ++k)
                    z[k] = fmaf(q, row[k * 64], z[k]);
            }
            #pragma unroll
            for (int k = 0; k < 8; ++k) sm.qp.red[w][k * 64 + lane] = z[k];
        }
        __syncthreads();
        {
            float acc = bi[t];
            #pragma unroll
            for (int ww = 0; ww < 8; ++ww) acc += sm.qp.red[ww][t];
            o[b * S_ + t] = acc;
        }
    }
    tgt += 256; gsync(sync_cnt, tgt);

    // ---------------- P1: prep_start (1024 logical, 4 per block) ----------
    for (int j = 0; j < 4; ++j) {
        __syncthreads();
        int lb = blk + 256 * j;
        int i = lb >> 6, b = lb & 63;
        fold_slice<false>(sm, i, b, W_qs, q_state, es, 0, Wc);
    }
    tgt += 256; gsync(sync_cnt, tgt);

    // ---------------- P2: score (start) ----------------
    score_phase<false>(sm, blk, es, Wc, qsi, W_ss, slen, nullptr, start_scores);
    tgt += 256; gsync(sync_cnt, tgt);

    // ---------------- P3: rescue (start), 512 logical ----------------
    for (int j = 0; j < 2; ++j) {
        __syncthreads();
        rescue_phase<false>(sm, blk + 256 * j, es, q_state, nullptr, W_qs, qsi, W_ss,
                            start_scores, part);
    }
    tgt += 256; gsync(sync_cnt, tgt);

    // ---------------- P4: prep_end + fused start-finalize (1024 logical) ---
    for (int j = 0; j < 4; ++j) {
        __syncthreads();
        int lb = blk + 256 * j;
        int i = lb >> 6, b = lb & 63;

        sm.pe.s_l[t] = start_scores[b * S_ + t];
        __syncthreads();
        int cnt = select_cands(sm.pe.s_l, t, lane, w, sm.pe.wred, sm.pe.wcnt, sm.pe.cand);
        if (t == 0) {
            int bi2 = sm.pe.cand[0];
            if (cnt > 1) {
                float bv = -INFINITY;
                for (int c = 0; c < cnt; ++c) {
                    float e = part[b * 8 + c];
                    if (e > bv) { bv = e; bi2 = sm.pe.cand[c]; }
                }
            }
            sm.pe.best_sh = bi2;
            if (i == 0) { pred_start[b] = (float)bi2; sp_ws[b] = bi2; }
        }
        __syncthreads();
        int best = sm.pe.best_sh;
        fold_slice<true>(sm, i, b, W_qe, q_state, es, best, Wc);
    }
    tgt += 256; gsync(sync_cnt, tgt);

    // ---------------- P5: score (end) ----------------
    score_phase<true>(sm, blk, es, Wc, qei, W_es, slen, sp_ws, end_scores);
    tgt += 256; gsync(sync_cnt, tgt);

    // ---------------- P6: rescue (end), 512 logical ----------------
    for (int j = 0; j < 2; ++j) {
        __syncthreads();
        rescue_phase<true>(sm, blk + 256 * j, es, q_state, sp_ws, W_qe, qei, W_es,
                           end_scores, part);
    }
    tgt += 256; gsync(sync_cnt, tgt);

    // ---------------- P7: finalize end (blocks 0..63) ----------------
    if (blk < 64) {
        int b = blk;
        sm.pe.s_l[t] = end_scores[b * S_ + t];
        __syncthreads();
        int cnt = select_cands(sm.pe.s_l, t, lane, w, sm.pe.wred, sm.pe.wcnt, sm.pe.cand);
        if (t == 0) {
            int bi2 = sm.pe.cand[0];
            if (cnt > 1) {
                float bv = -INFINITY;
                for (int c = 0; c < cnt; ++c) {
                    float e = part[b * 8 + c];
                    if (e > bv) { bv = e; bi2 = sm.pe.cand[c]; }
                }
            }
            pred_end[b] = (float)bi2;
        }
    }
}

// ---------------- launch ----------------
extern "C" void kernel_launch(void* const* d_in, const int* in_sizes, int n_in,
                              void* d_out, int out_size, void* d_ws, size_t ws_size,
                              hipStream_t stream)
{
    const float* eq    = (const float*)d_in[0];
    const float* es    = (const float*)d_in[1];
    const int*   qlen  = (const int*)d_in[2];
    const int*   slen  = (const int*)d_in[3];
    const float* W_qa  = (const float*)d_in[7];
    const float* W_qsi = (const float*)d_in[8];
    const float* b_qsi = (const float*)d_in[9];
    const float* W_qs  = (const float*)d_in[10];
    const float* W_ss  = (const float*)d_in[11];
    const float* W_qei = (const float*)d_in[12];
    const float* b_qei = (const float*)d_in[13];
    const float* W_qe  = (const float*)d_in[14];
    const float* W_es  = (const float*)d_in[15];

    float* out          = (float*)d_out;
    float* start_scores = out;
    float* end_scores   = out + B_ * LS_;
    float* pred_start   = out + 2 * B_ * LS_;
    float* pred_end     = out + 2 * B_ * LS_ + B_;

    float* ws      = (float*)d_ws;
    float* q_state = ws;                                 // [B,S]
    float* qsi     = ws + B_ * S_;                       // [B,S]
    float* qei     = ws + 2 * B_ * S_;                   // [B,S]
    float* part    = ws + 3 * B_ * S_;                   // [B,8]
    int*   sp_ws   = (int*)(ws + 3 * B_ * S_ + 512);     // [B]
    unsigned* sync = (unsigned*)(ws + 3 * B_ * S_ + 1024);
    short* Wc      = (short*)(ws + 3 * B_ * S_ + 2048);  // 33.5 MB

    hipMemsetAsync(sync, 0, 64, stream);
    mega_kernel<<<256, 512, 0, stream>>>(
        eq, es, qlen, slen, W_qa, W_qsi, b_qsi, W_qs, W_ss, W_qei, b_qei, W_qe, W_es,
        q_state, qsi, qei, part, sp_ws, Wc, sync,
        start_scores, end_scores, pred_start, pred_end);
}

// Round 23
// 160.190 us; speedup vs baseline: 7.5621x; 7.5621x over previous
//
#include <hip/hip_runtime.h>
#include <math.h>

constexpr int B_  = 64;
constexpr int LQ_ = 64;
constexpr int LS_ = 512;
constexpr int S_  = 512;
#define NEGV (-1e6f)
#define MARGIN 0.0625f

typedef __attribute__((ext_vector_type(8))) short bf16x8;
typedef __attribute__((ext_vector_type(4))) float f32x4;

__device__ inline unsigned short f2bf_rn(float x) {
    unsigned u = __builtin_bit_cast(unsigned, x);
    unsigned r = (u + 0x7FFFu + ((u >> 16) & 1u)) >> 16;
    return (unsigned short)r;
}

// -------- Kernel 1: qpool + one inter matrix per block (grid (B,2)) --------
__global__ __launch_bounds__(512)
void qpool_inter_kernel(const float* __restrict__ eq, const int* __restrict__ qlen,
                        const float* __restrict__ W_qa,
                        const float* __restrict__ W_qsi, const float* __restrict__ b_qsi,
                        const float* __restrict__ W_qei, const float* __restrict__ b_qei,
                        float* __restrict__ q_state,
                        float* __restrict__ qsi, float* __restrict__ qei)
{
    int b = blockIdx.x;
    int which = blockIdx.y;
    const float* W  = which ? W_qei : W_qsi;
    const float* bi = which ? b_qei : b_qsi;
    float*       o  = which ? qei   : qsi;

    int t = threadIdx.x, lane = t & 63, w = t >> 6;
    __shared__ float att[LQ_], wsm[LQ_], qs[S_];
    __shared__ float red[8][S_];
    const float* eqb = eq + (size_t)b * LQ_ * S_;

    #pragma unroll
    for (int k = 0; k < 8; ++k) {
        int q = w + 8 * k;
        const float* row = eqb + q * S_;
        float s = 0.f;
        #pragma unroll
        for (int j = 0; j < 8; ++j)
            s = fmaf(row[lane + 64 * j], W_qa[lane + 64 * j], s);
        #pragma unroll
        for (int off = 32; off >= 1; off >>= 1)
            s += __shfl_xor(s, off);
        if (lane == 0) att[q] = s;
    }
    __syncthreads();

    if (w == 0) {
        int L = qlen[b];
        float v = att[lane] + ((lane < L) ? 0.f : NEGV);
        float m = v;
        #pragma unroll
        for (int off = 32; off >= 1; off >>= 1)
            m = fmaxf(m, __shfl_xor(m, off));
        float e = expf(v - m);
        float sum = e;
        #pragma unroll
        for (int off = 32; off >= 1; off >>= 1)
            sum += __shfl_xor(sum, off);
        wsm[lane] = e / sum;
    }
    __syncthreads();

    {
        float acc = 0.f;
        #pragma unroll 8
        for (int q = 0; q < LQ_; ++q)
            acc = fmaf(wsm[q], eqb[q * S_ + t], acc);
        qs[t] = acc;
        if (which == 0) q_state[b * S_ + t] = acc;
    }
    __syncthreads();

    // inter: wave w covers ALL 512 cols for its 64-d slice
    {
        float z[8];
        #pragma unroll
        for (int k = 0; k < 8; ++k) z[k] = 0.f;
        const int d0 = w * 64;
        #pragma unroll 4
        for (int dd = 0; dd < 64; ++dd) {
            int d = d0 + dd;
            float q = qs[d];
            const float* row = W + (size_t)d * S_ + lane;
            #pragma unroll
            for (int k = 0; k < 8; ++k)
                z[k] = fmaf(q, row[k * 64], z[k]);
        }
        #pragma unroll
        for (int k = 0; k < 8; ++k) red[w][k * 64 + lane] = z[k];
    }
    __syncthreads();
    {
        float acc = bi[t];
        #pragma unroll
        for (int ww = 0; ww < 8; ++ww) acc += red[ww][t];
        o[b * S_ + t] = acc;
    }
}

// ---------------- Kernel P: per-batch folded weight prep (bf16, RN) --------
// Wc layout: [b][i][kc][col][8] shorts; base = b*262144 + i*16384 + col*8,
// element kc at +kc*4096.  D = i*32 + kc*8 + e.
template <int NT>
__global__ __launch_bounds__(512)
void prep_kernel(const float* __restrict__ W, const float* __restrict__ q_state,
                 const float* __restrict__ u_s, short* __restrict__ Wc)
{
    int bid = blockIdx.x;
    int i = bid >> 6, b = bid & 63;     // 64 consecutive blocks share W slice (L2)
    int col = threadIdx.x;
    __shared__ float scq[32], scu[32];
    if (col < 32) scq[col] = q_state[b * S_ + i * 32 + col];
    if (NT == 3 && col >= 32 && col < 64) scu[col - 32] = u_s[b * S_ + i * 32 + col - 32];
    __syncthreads();

    unsigned short h[32];
    #pragma unroll
    for (int d = 0; d < 32; ++d) {
        int D = i * 32 + d;
        float v;
        if (NT == 2)
            v = fmaf(scq[d], W[(size_t)D * S_ + col], W[(size_t)(S_ + D) * S_ + col]);
        else
            v = fmaf(scu[d], W[(size_t)D * S_ + col],
                fmaf(scq[d], W[(size_t)(S_ + D) * S_ + col], W[(size_t)(2 * S_ + D) * S_ + col]));
        h[d] = f2bf_rn(v);
    }
    size_t base = (size_t)b * 262144 + (size_t)i * 16384 + (size_t)col * 8;
    #pragma unroll
    for (int kc = 0; kc < 4; ++kc) {
        uint4 H;
        H.x = h[kc*8+0] | ((unsigned)h[kc*8+1] << 16);
        H.y = h[kc*8+2] | ((unsigned)h[kc*8+3] << 16);
        H.z = h[kc*8+4] | ((unsigned)h[kc*8+5] << 16);
        H.w = h[kc*8+6] | ((unsigned)h[kc*8+7] << 16);
        *(uint4*)&Wc[base + kc * 4096] = H;
    }
}

// -------- Kernel S: 128x512 bf16 MFMA score; reg-staged B, 1 barrier/step --
// Grid 256 = 4rc x 64b XCD-grouped; 8 waves = 2wr x 4wc; wave 64r x 128c.
template <bool END>
__global__ __launch_bounds__(512)
void score_kernel(const float* __restrict__ es, const short* __restrict__ Wc,
                  const float* __restrict__ inter, const float* __restrict__ Wsmall,
                  const int* __restrict__ slen, const int* __restrict__ sp,
                  float* __restrict__ out)
{
    const int t = threadIdx.x;
    const int lane = t & 63, wid = t >> 6;
    const int wr = wid >> 2, wc = wid & 3;
    const int l15 = lane & 15, l4 = lane >> 4;

    int lid = blockIdx.x;
    int xcd = lid & 7, slot = lid >> 3;
    int b  = xcd * 8 + (slot >> 2);
    int rc = slot & 3;

    __shared__ __attribute__((aligned(16))) short As[2][4096];   // 16 KB
    __shared__ __attribute__((aligned(16))) short Bs[2][16384];  // 64 KB
    __shared__ float int_l[S_], wsm_l[S_];
    __shared__ float sm_red[128][4];

    int_l[t] = inter[b * S_ + t];
    wsm_l[t] = Wsmall[t];

    const char* Bbase = (const char*)(Wc + (size_t)b * 262144);

    f32x4 acc[4][8];
    #pragma unroll
    for (int r = 0; r < 4; ++r)
        #pragma unroll
        for (int c = 0; c < 8; ++c)
            acc[r][c] = (f32x4){0.f, 0.f, 0.f, 0.f};

    const int arow = t >> 2, akc = t & 3;
    const float* aptr = es + ((size_t)(b * LS_ + rc * 128 + arow)) * S_ + akc * 8;

    auto buildA = [&](int buf, float4 a0, float4 a1) {
        uint4 HA;
        HA.x = f2bf_rn(a0.x) | ((unsigned)f2bf_rn(a0.y) << 16);
        HA.y = f2bf_rn(a0.z) | ((unsigned)f2bf_rn(a0.w) << 16);
        HA.z = f2bf_rn(a1.x) | ((unsigned)f2bf_rn(a1.y) << 16);
        HA.w = f2bf_rn(a1.z) | ((unsigned)f2bf_rn(a1.w) << 16);
        *(uint4*)&As[buf][akc * 1024 + arow * 8] = HA;
    };

    // prologue: B(0) and A(0) to regs; prefetch A(1)
    uint4 G0, G1, G2, G3;
    {
        const char* gb = Bbase + t * 16;
        G0 = *(const uint4*)(gb);
        G1 = *(const uint4*)(gb + 8192);
        G2 = *(const uint4*)(gb + 16384);
        G3 = *(const uint4*)(gb + 24576);
    }
    float4 a0 = *(const float4*)(aptr);
    float4 a1 = *(const float4*)(aptr + 4);
    float4 n0 = *(const float4*)(aptr + 32);
    float4 n1 = *(const float4*)(aptr + 36);

    for (int i = 0; i < 16; ++i) {
        const int buf = i & 1;

        // issue next B-tile loads (load-use distance = one full iteration)
        uint4 N0, N1, N2, N3;
        if (i + 1 < 16) {
            const char* gb = Bbase + (size_t)(i + 1) * 32768 + t * 16;
            N0 = *(const uint4*)(gb);
            N1 = *(const uint4*)(gb + 8192);
            N2 = *(const uint4*)(gb + 16384);
            N3 = *(const uint4*)(gb + 24576);
        }

        // write current B tile + A tile (G/a regs loaded one iteration ago)
        {
            char* lb = (char*)Bs[buf] + t * 16;
            *(uint4*)(lb)         = G0;
            *(uint4*)(lb + 8192)  = G1;
            *(uint4*)(lb + 16384) = G2;
            *(uint4*)(lb + 24576) = G3;
        }
        buildA(buf, a0, a1);

        // rotate prefetch registers
        a0 = n0; a1 = n1;
        if (i + 2 < 16) {
            n0 = *(const float4*)(aptr + (i + 2) * 32);
            n1 = *(const float4*)(aptr + (i + 2) * 32 + 4);
        }
        G0 = N0; G1 = N1; G2 = N2; G3 = N3;

        asm volatile("s_waitcnt lgkmcnt(0)" ::: "memory");
        __builtin_amdgcn_s_barrier();

        bf16x8 ah[4];
        #pragma unroll
        for (int r = 0; r < 4; ++r) {
            int rowp = wr * 64 + r * 16 + l15;
            ah[r] = *(const bf16x8*)&As[buf][l4 * 1024 + rowp * 8];
        }
        #pragma unroll
        for (int c = 0; c < 8; ++c) {
            int col = wc * 128 + c * 16 + l15;
            bf16x8 bh = *(const bf16x8*)&Bs[buf][l4 * 4096 + col * 8];
            #pragma unroll
            for (int r = 0; r < 4; ++r)
                acc[r][c] = __builtin_amdgcn_mfma_f32_16x16x32_bf16(ah[r], bh, acc[r][c], 0, 0, 0);
        }
        // no second barrier: double-buffering + next iteration's pre-write
        // barrier orders write(i+2) after all reads(i).
    }

    // epilogue: + inter, relu, dot Wsmall, row reduce, masks, store
    #pragma unroll
    for (int r = 0; r < 4; ++r) {
        #pragma unroll
        for (int jj = 0; jj < 4; ++jj) {
            float pr = 0.f;
            #pragma unroll
            for (int c = 0; c < 8; ++c) {
                int col = wc * 128 + c * 16 + l15;
                float v = acc[r][c][jj] + int_l[col];
                v = fmaxf(v, 0.f);
                pr = fmaf(v, wsm_l[col], pr);
            }
            pr += __shfl_xor(pr, 1);
            pr += __shfl_xor(pr, 2);
            pr += __shfl_xor(pr, 4);
            pr += __shfl_xor(pr, 8);
            if (l15 == 0) sm_red[wr * 64 + r * 16 + l4 * 4 + jj][wc] = pr;
        }
    }
    __syncthreads();
    if (t < 128) {
        int l = rc * 128 + t;
        float s = sm_red[t][0] + sm_red[t][1] + sm_red[t][2] + sm_red[t][3];
        if (l >= slen[b]) s += NEGV;
        if (END) { if (l < sp[b]) s += NEGV; }
        out[b * LS_ + l] = s;
    }
}

// ---------------- candidate selection ----------------
__device__ inline int select_cands(const float* s_l, int t, int lane, int w,
                                   float* wred, int* wcnt, int* cand)
{
    float v = s_l[t];
    #pragma unroll
    for (int off = 32; off >= 1; off >>= 1)
        v = fmaxf(v, __shfl_xor(v, off));
    if (lane == 0) wred[w] = v;
    __syncthreads();
    float m = wred[0];
    #pragma unroll
    for (int k = 1; k < 8; ++k) m = fmaxf(m, wred[k]);
    float th = m - MARGIN;
    bool flag = s_l[t] >= th;
    unsigned long long bal = __ballot(flag);
    int rank = __popcll(bal & ((1ull << lane) - 1ull));
    if (lane == 0) wcnt[w] = (int)__popcll(bal);
    __syncthreads();
    int off = 0, total = 0;
    #pragma unroll
    for (int k = 0; k < 8; ++k) { if (k < w) off += wcnt[k]; total += wcnt[k]; }
    if (flag) { int pos = off + rank; if (pos < 8) cand[pos] = t; }
    __syncthreads();
    return total < 8 ? total : 8;
}

// ---------------- Kernel R: exact rescue, one candidate per block ----------
template <bool END>
__global__ __launch_bounds__(512)
void rescue_kernel(const float* __restrict__ support, const float* __restrict__ q_state,
                   const float* __restrict__ u_s_in, const float* __restrict__ Wbig,
                   const float* __restrict__ inter, const float* __restrict__ Wsmall,
                   const float* __restrict__ scores, float* __restrict__ part)
{
    int bid = blockIdx.x;
    int b = bid >> 3, cslot = bid & 7;
    int t = threadIdx.x, lane = t & 63, w = t >> 6;
    __shared__ float s_l[S_], qs_l[S_], us_l[S_], arow_sh[S_];
    __shared__ float red[8][S_];
    __shared__ float wred[8];
    __shared__ int wcnt[8], cand[8];

    s_l[t]  = scores[b * S_ + t];
    qs_l[t] = q_state[b * S_ + t];
    if (END) us_l[t] = u_s_in[b * S_ + t];
    __syncthreads();

    int cnt = select_cands(s_l, t, lane, w, wred, wcnt, cand);
    if (cnt == 1 || cslot >= cnt) return;

    int ci = cand[cslot];
    arow_sh[t] = support[((size_t)(b * LS_ + ci)) * S_ + t];
    __syncthreads();

    const float* W1 = Wbig;
    const float* W2 = Wbig + (size_t)S_ * S_;
    const float* W3 = Wbig + (size_t)2 * S_ * S_;
    const int d0 = w * 64;

    float z[8];
    #pragma unroll
    for (int j = 0; j < 8; ++j) z[j] = 0.f;

    #pragma unroll 2
    for (int dd = 0; dd < 64; ++dd) {
        int d = d0 + dd;
        float a  = arow_sh[d];
        float qa = qs_l[d] * a;
        float ua = END ? us_l[d] * a : 0.f;
        const float* r1 = W1 + (size_t)d * S_ + lane;
        const float* r2 = W2 + (size_t)d * S_ + lane;
        const float* r3 = W3 + (size_t)d * S_ + lane;
        #pragma unroll
        for (int j = 0; j < 8; ++j) {
            if (END)
                z[j] = fmaf(ua, r1[64 * j], fmaf(qa, r2[64 * j], fmaf(a, r3[64 * j], z[j])));
            else
                z[j] = fmaf(qa, r1[64 * j], fmaf(a, r2[64 * j], z[j]));
        }
    }
    #pragma unroll
    for (int j = 0; j < 8; ++j) red[w][lane + 64 * j] = z[j];
    __syncthreads();

    float v = 0.f;
    #pragma unroll
    for (int ww = 0; ww < 8; ++ww) v += red[ww][t];
    float p = fmaxf(v + inter[b * S_ + t], 0.f) * Wsmall[t];
    #pragma unroll
    for (int off = 32; off >= 1; off >>= 1)
        p += __shfl_xor(p, off);
    if (lane == 0) wred[w] = p;
    __syncthreads();
    if (t == 0) {
        float e = ((wred[0] + wred[1]) + (wred[2] + wred[3])) +
                  ((wred[4] + wred[5]) + (wred[6] + wred[7]));
        part[b * 8 + cslot] = e;
    }
}

// ---------------- Kernel F: finalize (exact argmax, sp/u_s/pred) ----------
template <bool END>
__global__ __launch_bounds__(512)
void finalize_kernel(const float* __restrict__ scores, const float* __restrict__ part,
                     const float* __restrict__ support, int* __restrict__ sp_ws,
                     float* __restrict__ pred, float* __restrict__ us_out)
{
    int b = blockIdx.x;
    int t = threadIdx.x, lane = t & 63, w = t >> 6;
    __shared__ float s_l[S_];
    __shared__ float wred[8];
    __shared__ int wcnt[8], cand[8];
    __shared__ int best_sh;

    s_l[t] = scores[b * S_ + t];
    __syncthreads();
    int cnt = select_cands(s_l, t, lane, w, wred, wcnt, cand);

    if (t == 0) {
        int bi = cand[0];
        if (cnt > 1) {
            float bv = -INFINITY;
            for (int c = 0; c < cnt; ++c) {
                float e = part[b * 8 + c];
                if (e > bv) { bv = e; bi = cand[c]; }
            }
        }
        best_sh = bi;
        pred[b] = (float)bi;
        if (!END) sp_ws[b] = bi;
    }
    __syncthreads();
    if (!END)
        us_out[b * S_ + t] = support[((size_t)(b * LS_ + best_sh)) * S_ + t];
}

// ---------------- launch ----------------
extern "C" void kernel_launch(void* const* d_in, const int* in_sizes, int n_in,
                              void* d_out, int out_size, void* d_ws, size_t ws_size,
                              hipStream_t stream)
{
    const float* eq    = (const float*)d_in[0];
    const float* es    = (const float*)d_in[1];
    const int*   qlen  = (const int*)d_in[2];
    const int*   slen  = (const int*)d_in[3];
    const float* W_qa  = (const float*)d_in[7];
    const float* W_qsi = (const float*)d_in[8];
    const float* b_qsi = (const float*)d_in[9];
    const float* W_qs  = (const float*)d_in[10];
    const float* W_ss  = (const float*)d_in[11];
    const float* W_qei = (const float*)d_in[12];
    const float* b_qei = (const float*)d_in[13];
    const float* W_qe  = (const float*)d_in[14];
    const float* W_es  = (const float*)d_in[15];

    float* out          = (float*)d_out;
    float* start_scores = out;
    float* end_scores   = out + B_ * LS_;
    float* pred_start   = out + 2 * B_ * LS_;
    float* pred_end     = out + 2 * B_ * LS_ + B_;

    float* ws      = (float*)d_ws;
    float* q_state = ws;                       // [B,S]
    float* qsi     = ws + B_ * S_;             // [B,S]
    float* qei     = ws + 2 * B_ * S_;         // [B,S]
    float* u_s     = ws + 3 * B_ * S_;         // [B,S]
    float* part    = ws + 4 * B_ * S_;         // [B,8]
    int*   sp_ws   = (int*)(ws + 4 * B_ * S_ + 512);    // [B]
    short* Wc      = (short*)(ws + 4 * B_ * S_ + 1024); // 33.5 MB

    qpool_inter_kernel<<<dim3(B_, 2), 512, 0, stream>>>(
        eq, qlen, W_qa, W_qsi, b_qsi, W_qei, b_qei, q_state, qsi, qei);

    // ---- start pass ----
    prep_kernel<2><<<1024, 512, 0, stream>>>(W_qs, q_state, nullptr, Wc);
    score_kernel<false><<<256, 512, 0, stream>>>(es, Wc, qsi, W_ss, slen, nullptr, start_scores);
    rescue_kernel<false><<<B_ * 8, 512, 0, stream>>>(es, q_state, nullptr, W_qs, qsi, W_ss,
                                                     start_scores, part);
    finalize_kernel<false><<<B_, 512, 0, stream>>>(start_scores, part, es, sp_ws, pred_start, u_s);

    // ---- end pass ----
    prep_kernel<3><<<1024, 512, 0, stream>>>(W_qe, q_state, u_s, Wc);
    score_kernel<true><<<256, 512, 0, stream>>>(es, Wc, qei, W_es, slen, sp_ws, end_scores);
    rescue_kernel<true><<<B_ * 8, 512, 0, stream>>>(es, q_state, u_s, W_qe, qei, W_es,
                                                    end_scores, part);
    finalize_kernel<true><<<B_, 512, 0, stream>>>(end_scores, part, es, nullptr, pred_end, nullptr);
}